// Round 19
// baseline (66.635 us; speedup 1.0000x reference)
//
#include <hip/hip_runtime.h>
#include <hip/hip_bf16.h>

#define HW 3136            // 56*56
#define NPIX 50176         // 16*3136

typedef __attribute__((ext_vector_type(8))) _Float16 f16x8;
typedef __attribute__((ext_vector_type(4))) float f32x4;
typedef __attribute__((ext_vector_type(8))) unsigned short u16x8;

__device__ inline unsigned short f2h(float v){
    _Float16 h = (_Float16)v;
    union { _Float16 h; unsigned short u; } cv; cv.h = h; return cv.u;
}
__device__ inline float h2f(unsigned short u){
    union { unsigned short u; _Float16 h; } cv; cv.u = u; return (float)cv.h;
}

// ================= fused prep (r16-proven, unchanged) =================
// A (blocks 0..391):   x -> xg[(b*2+g)][s][32ic fp16]
// B (blocks 392..663): x -> xpad[plane][68][72] fp16, zero halo
// C (blocks 664..859): w1 -> w1t[g][tap][oc][32ic] fp16  (parallel: thread per octet)
__global__ __launch_bounds__(256) void prep_all(
    const float* __restrict__ x, const float* __restrict__ w1,
    unsigned short* __restrict__ xg, unsigned short* __restrict__ w1t,
    unsigned short* __restrict__ xpad)
{
    int bb = blockIdx.x;
    if (bb < 392) {
        int t = bb * 256 + threadIdx.x;           // < 100352
        int g = t / NPIX;
        int pix = t - g * NPIX;
        int b = pix / HW; int s = pix - b * HW;
        const float* xp = x + (size_t)b * 64 * HW + (size_t)g * 32 * HW + s;
        unsigned short* dst = xg + ((size_t)(b * 2 + g) * HW + s) * 32;
#pragma unroll
        for (int p = 0; p < 4; ++p) {
            alignas(16) unsigned short tmp[8];
#pragma unroll
            for (int e = 0; e < 8; ++e)
                tmp[e] = f2h(xp[(size_t)(p * 8 + e) * HW]);
            *(u16x8*)(dst + p * 8) = *(const u16x8*)tmp;
        }
    } else if (bb < 664) {
        int t2 = (bb - 392) * 256 + threadIdx.x;  // < 69632
        int plane = t2 / 68; int r = t2 - plane * 68;
        unsigned short* dst = xpad + ((size_t)plane * 68 + r) * 72;
        int h = r - 6;
        alignas(16) unsigned short tmp[72];
#pragma unroll
        for (int i = 0; i < 72; ++i) tmp[i] = 0;
        if (h >= 0 && h < 56) {
            const float* src = x + (size_t)plane * HW + h * 56;
#pragma unroll
            for (int wq = 0; wq < 56; ++wq) tmp[6 + wq] = f2h(src[wq]);
        }
#pragma unroll
        for (int k = 0; k < 9; ++k)
            *(u16x8*)(dst + k * 8) = *(const u16x8*)(tmp + k * 8);
    } else {
        int t = (bb - 664) * 256 + threadIdx.x;   // < 50176 = 2*49*128*4
        int g = t / 25088;
        int r = t - g * 25088;                    // tap*512 + oc*4 + jo
        int tap = r / 512; int r2 = r - tap * 512;
        int oc = r2 >> 2; int jo = r2 & 3;
        unsigned short* dst = w1t + ((size_t)(g * 49 + tap) * 128 + oc) * 32 + jo * 8;
        alignas(16) unsigned short tmp[8];
#pragma unroll
        for (int e = 0; e < 8; ++e)
            tmp[e] = f2h(w1[((size_t)(oc * 64 + g * 32 + jo * 8 + e)) * 49 + tap]);
        *(u16x8*)dst = *(const u16x8*)tmp;
    }
}

// ================= conv1(full K, dual-resident halves) + conv2 + softmax =================
// grid 224 = (b16, rg14); block 512 = 8 waves; waves 0-3: g=0, waves 4-7: g=1
// r18 structure; tap loop UNPINNED (no sched_barrier) — compiler schedules freely
// attn output: [g][56-pad] fp16 where g = flat([B,49,HW])/49 (= out-flat/64 space)
// LDS: 2 planes x 16rows x 68sites x 72B = 156672 B (1 block/CU)
#define LOADA(Abuf, tap) do {                                                 \
    const int p_ = (tap) / 7, q_ = (tap) - 7 * ((tap) / 7);                   \
    const int off_ = p_ * 9792 + q_ * 144;                                    \
    _Pragma("unroll")                                                         \
    for (int mt = 0; mt < 7; ++mt)                                            \
        Abuf[mt] = *(const f16x8*)(smem + abase[mt] + off_);                  \
    } while (0)

#define LOADB(Bbuf, tap) do {                                                 \
    const unsigned short* p_ = wb + (size_t)(tap) * 4096;                     \
    Bbuf[0] = *(const f16x8*)(p_);                                            \
    Bbuf[1] = *(const f16x8*)(p_ + 512);                                      \
    Bbuf[2] = *(const f16x8*)(p_ + 1024);                                     \
    Bbuf[3] = *(const f16x8*)(p_ + 1536);                                     \
    } while (0)

#define DOMFMA(Abuf, Bbuf) do {                                               \
    _Pragma("unroll")                                                         \
    for (int mt = 0; mt < 7; ++mt) {                                          \
        acc[mt][0] = __builtin_amdgcn_mfma_f32_16x16x32_f16(Abuf[mt], Bbuf[0], acc[mt][0], 0, 0, 0); \
        acc[mt][1] = __builtin_amdgcn_mfma_f32_16x16x32_f16(Abuf[mt], Bbuf[1], acc[mt][1], 0, 0, 0); \
        acc[mt][2] = __builtin_amdgcn_mfma_f32_16x16x32_f16(Abuf[mt], Bbuf[2], acc[mt][2], 0, 0, 0); \
        acc[mt][3] = __builtin_amdgcn_mfma_f32_16x16x32_f16(Abuf[mt], Bbuf[3], acc[mt][3], 0, 0, 0); \
    }                                                                         \
    } while (0)

__global__ __launch_bounds__(512, 2) void conv_full(
    const unsigned short* __restrict__ xg, const unsigned short* __restrict__ w1t,
    const float* __restrict__ b1, const float* __restrict__ w2,
    const float* __restrict__ b2, unsigned short* __restrict__ attn2)
{
    __shared__ char smem[156672];                      // 2 x 78336
    unsigned short* k1sa = (unsigned short*)smem;            // [224][136] 60928 B (epilogue)
    unsigned short* w2s  = (unsigned short*)(smem + 60928);  // [64][136]  17408 B
    unsigned short* k1sb = (unsigned short*)(smem + 78336);  // [224][136] 60928 B

    const int blk = blockIdx.x;
    const int b   = blk / 14; const int rg = blk - b * 14;
    const int h0  = rg * 4;
    const int tid = threadIdx.x;
    const int lane = tid & 63, warp = tid >> 6;        // 8 waves
    const int g   = warp >> 2;                         // ic-half
    const int wm  = (warp >> 1) & 1, wn = warp & 1;
    const int oc0 = wn * 64;
    const int li  = lane & 15, j = lane >> 4;

    const unsigned short* xplane[2] = {
        xg + (size_t)(b * 2 + 0) * HW * 32,
        xg + (size_t)(b * 2 + 1) * HW * 32 };

    u16x8 zz; for (int e = 0; e < 8; ++e) zz[e] = 0;

    // ---- issue staged loads for BOTH planes (14 x 16B per thread) ----
    u16x8 sv[14];
#pragma unroll
    for (int u = 0; u < 14; ++u) {
        int i = u * 512 + tid;                         // < 7168 = 2*16*224
        int pl = i / 3584; int rem = i - pl * 3584;
        int row = rem / 224; int r2 = rem - row * 224;
        int site = r2 >> 2, chunk = r2 & 3;
        int hh = h0 - 6 + row;
        sv[u] = (hh >= 0 && hh < 56)
            ? *(const u16x8*)(xplane[pl] + ((size_t)hh * 56 + site) * 32 + chunk * 8)
            : zz;
    }

    // ---- zero all LDS (halos stay zero) ----
    {
        f32x4 zv = {0.f, 0.f, 0.f, 0.f};
#pragma unroll
        for (int u = 0; u < 20; ++u) {
            int i = u * 512 + tid;
            if (i < 9792) *(f32x4*)(smem + (size_t)i * 16) = zv;
        }
    }
    __syncthreads();

    // ---- write staged tiles (site stride 72B) ----
#pragma unroll
    for (int u = 0; u < 14; ++u) {
        int i = u * 512 + tid;
        int pl = i / 3584; int rem = i - pl * 3584;
        int row = rem / 224; int r2 = rem - row * 224;
        int site = r2 >> 2, chunk = r2 & 3;
        int hh = h0 - 6 + row;
        if (hh >= 0 && hh < 56)
            *(u16x8*)(smem + pl * 78336 + (row * 68 + 6 + site) * 72 + chunk * 16) = sv[u];
    }

    // ---- issue w2 loads (latency hidden under tap loop) ----
    f32x4 wv[4];
#pragma unroll
    for (int u = 0; u < 4; ++u) {
        int idx = u * 512 + tid;                       // f32x4 index, < 1568
        wv[u] = (idx < 1568) ? *(const f32x4*)(w2 + (size_t)idx * 4)
                             : (f32x4){0.f, 0.f, 0.f, 0.f};
    }
    __syncthreads();

    // ---- A base addresses (fixed across all taps; include plane offset) ----
    int abase[7];
#pragma unroll
    for (int mt = 0; mt < 7; ++mt) {
        int local = wm * 112 + mt * 16 + li;           // 0..223
        int rb = local / 56; int wp = local - rb * 56;
        abase[mt] = g * 78336 + (rb * 68 + wp) * 72 + j * 16;
    }

    f32x4 acc[7][4];
#pragma unroll
    for (int mt = 0; mt < 7; ++mt)
#pragma unroll
        for (int nt = 0; nt < 4; ++nt)
#pragma unroll
            for (int c = 0; c < 4; ++c) acc[mt][nt][c] = 0.f;

    // B base: w1t[g][tap][oc][32], oc = oc0 + li (+nt*16 via imm)
    const unsigned short* wb = w1t + ((size_t)g * 49 * 128 + oc0 + li) * 32 + j * 8;

    // ---- 49-tap fully-unrolled loop, 1-tap double buffer, UNPINNED ----
    {
        f16x8 A0[7], A1[7], B0[4], B1[4];
        LOADA(A0, 0); LOADB(B0, 0);
#pragma unroll
        for (int th = 0; th < 24; ++th) {
            LOADA(A1, 2 * th + 1); LOADB(B1, 2 * th + 1);
            DOMFMA(A0, B0);
            LOADA(A0, 2 * th + 2); LOADB(B0, 2 * th + 2);
            DOMFMA(A1, B1);
        }
        DOMFMA(A0, B0);                                // tap 48
    }

    __syncthreads();          // all staging readers done; LDS can be overlaid

    // ---- epilogue phase A: write k1 partials + w2s ----
    // g0 waves -> k1sa (+bias); g1 waves -> k1sb (no bias)
    {
        unsigned short* kb = g ? k1sb : k1sa;
        const int pixbase = wm * 112;
#pragma unroll
        for (int nt = 0; nt < 4; ++nt) {
            int oc = oc0 + nt * 16 + li;
            float bias = g ? 0.f : b1[oc];
#pragma unroll
            for (int mt = 0; mt < 7; ++mt) {
#pragma unroll
                for (int i = 0; i < 4; ++i) {
                    int px = pixbase + mt * 16 + j * 4 + i;
                    kb[px * 136 + oc] = f2h(acc[mt][nt][i] + bias);
                }
            }
        }
    }
    // w2s [64 taps][136] fp16 (rows >=49 garbage, masked later)
#pragma unroll
    for (int u = 0; u < 4; ++u) {
        int idx = u * 512 + tid;
        if (idx < 1568) {
            int a = idx / 32; int c0 = (idx - a * 32) * 4;
            alignas(8) unsigned short t4[4];
#pragma unroll
            for (int e = 0; e < 4; ++e) t4[e] = f2h(wv[u][e]);
            *(unsigned long long*)(w2s + a * 136 + c0) = *(const unsigned long long*)t4;
        }
    }
    __syncthreads();

    // ---- conv2: L[tap][px] = w2 @ (k1a + k1b), softmax over taps ----
    // output: attn2[g][56] fp16 with g = b*3136 + 64*r + s/49, col = s%49
    const int start = (warp < 6) ? warp * 2 : 12 + (warp - 6);
    const int cnt   = (warp < 6) ? 2 : 1;

#pragma unroll
    for (int u = 0; u < 2; ++u) {
        if (u < cnt) {
            int pxt = start + u;
            f32x4 a2[4];
#pragma unroll
            for (int tt = 0; tt < 4; ++tt)
#pragma unroll
                for (int c = 0; c < 4; ++c) a2[tt][c] = 0.f;
#pragma unroll
            for (int ks = 0; ks < 4; ++ks) {
                const f16x8 ba = *(const f16x8*)(k1sa + (pxt * 16 + li) * 136 + ks * 32 + j * 8);
                const f16x8 bbv = *(const f16x8*)(k1sb + (pxt * 16 + li) * 136 + ks * 32 + j * 8);
                const f16x8 bf = ba + bbv;             // packed fp16 add
#pragma unroll
                for (int tt = 0; tt < 4; ++tt) {
                    const f16x8 af = *(const f16x8*)(w2s + (tt * 16 + li) * 136 + ks * 32 + j * 8);
                    a2[tt] = __builtin_amdgcn_mfma_f32_16x16x32_f16(af, bf, a2[tt], 0, 0, 0);
                }
            }
            // softmax over taps (rows) for pixel col li
            float mx = -3e38f;
#pragma unroll
            for (int tt = 0; tt < 4; ++tt)
#pragma unroll
                for (int i = 0; i < 4; ++i) {
                    int r = tt * 16 + j * 4 + i;
                    float v = a2[tt][i] + ((r < 49) ? b2[r] : 0.f);
                    a2[tt][i] = v;
                    if (r < 49) mx = fmaxf(mx, v);
                }
            mx = fmaxf(mx, __shfl_xor(mx, 16));
            mx = fmaxf(mx, __shfl_xor(mx, 32));
            float sum = 0.f; float ex[16];
#pragma unroll
            for (int tt = 0; tt < 4; ++tt)
#pragma unroll
                for (int i = 0; i < 4; ++i) {
                    int r = tt * 16 + j * 4 + i;
                    float e = (r < 49) ? __expf(a2[tt][i] - mx) : 0.f;
                    ex[tt * 4 + i] = e; sum += e;
                }
            sum += __shfl_xor(sum, 16);
            sum += __shfl_xor(sum, 32);
            float inv = 1.f / sum;

            int s = rg * 224 + pxt * 16 + li;          // pixel within batch
            int s49 = s / 49; int sm = s - s49 * 49;
            unsigned short* ab2 = attn2 + ((size_t)b * 3136 + s49) * 56 + sm;
#pragma unroll
            for (int tt = 0; tt < 4; ++tt)
#pragma unroll
                for (int i = 0; i < 4; ++i) {
                    int r = tt * 16 + j * 4 + i;
                    if (r < 49) ab2[(size_t)r * 3584] = f2h(ex[tt * 4 + i] * inv);
                }
        }
    }
}

// ================= final grouped einsum, 8 outputs/thread; vectorized attn2 reads =================
__global__ __launch_bounds__(256) void gather_kernel(
    const unsigned short* __restrict__ xpad, const unsigned short* __restrict__ attn2,
    float* __restrict__ out)
{
    int tid = blockIdx.x * 256 + threadIdx.x;   // < 401408
    int plane = tid / 392;                      // b*64 + c
    int r1 = tid - plane * 392;
    int h = r1 / 7; int oct = r1 - h * 7; int w0 = oct * 8;
    int F0 = plane * HW + h * 56 + w0;

    // attn2[g][56], 16B-aligned rows (112B): 7 vector loads replace 49 scalars
    const unsigned short* ap = attn2 + (size_t)(F0 >> 6) * 56;
    u16x8 av[7];
#pragma unroll
    for (int u = 0; u < 7; ++u) av[u] = *(const u16x8*)(ap + u * 8);
    float a[49];
#pragma unroll
    for (int k = 0; k < 49; ++k) a[k] = h2f(av[k >> 3][k & 7]);

    const unsigned short* xp = xpad + (size_t)plane * (68 * 72) + w0;
    float o[8];
#pragma unroll
    for (int dw = 0; dw < 8; ++dw) o[dw] = 0.f;

#pragma unroll
    for (int p = 0; p < 7; ++p) {
        const unsigned short* rp = xp + (h + 2 * p) * 72;
        u16x8 v0 = *(const u16x8*)rp;
        u16x8 v1 = *(const u16x8*)(rp + 8);
        u16x8 v2 = *(const u16x8*)(rp + 16);
        float rr[20];
#pragma unroll
        for (int e = 0; e < 8; ++e) { rr[e] = h2f(v0[e]); rr[8 + e] = h2f(v1[e]); }
#pragma unroll
        for (int e = 0; e < 4; ++e) rr[16 + e] = h2f(v2[e]);
#pragma unroll
        for (int q = 0; q < 7; ++q) {
            float aq = a[p * 7 + q];
#pragma unroll
            for (int dw = 0; dw < 8; ++dw)
                o[dw] = fmaf(rr[dw + 2 * q], aq, o[dw]);
        }
    }

    f32x4 s0 = {o[0], o[1], o[2], o[3]};
    f32x4 s1 = {o[4], o[5], o[6], o[7]};
    *(f32x4*)(out + F0) = s0;
    *(f32x4*)(out + F0 + 4) = s1;
}

extern "C" void kernel_launch(void* const* d_in, const int* in_sizes, int n_in,
                              void* d_out, int out_size, void* d_ws, size_t ws_size,
                              hipStream_t stream)
{
    const float* x  = (const float*)d_in[0];
    const float* w1 = (const float*)d_in[1];
    const float* b1 = (const float*)d_in[2];
    const float* w2 = (const float*)d_in[3];
    const float* b2 = (const float*)d_in[4];
    float* out = (float*)d_out;

    unsigned short* attn2 = (unsigned short*)d_ws;             //  5.62 MB (50176 x 56 fp16)
    unsigned short* xg    = attn2 + (size_t)NPIX * 56;         //  6.42 MB
    unsigned short* w1t   = xg + (size_t)16 * 2 * HW * 32;     //  0.80 MB
    unsigned short* xpad  = w1t + (size_t)2 * 49 * 128 * 32;   // 10.03 MB (total ~22.9 MB)

    prep_all<<<860, 256, 0, stream>>>(x, w1, xg, w1t, xpad);
    conv_full<<<224, 512, 0, stream>>>(xg, w1t, b1, w2, b2, attn2);
    gather_kernel<<<1568, 256, 0, stream>>>(xpad, attn2, out);
}

// Round 20
// 64.918 us; speedup vs baseline: 1.0264x; 1.0264x over previous
//
#include <hip/hip_runtime.h>
#include <hip/hip_bf16.h>

#define HW 3136            // 56*56
#define NPIX 50176         // 16*3136

typedef __attribute__((ext_vector_type(8))) _Float16 f16x8;
typedef __attribute__((ext_vector_type(4))) float f32x4;
typedef __attribute__((ext_vector_type(8))) unsigned short u16x8;

__device__ inline unsigned short f2h(float v){
    _Float16 h = (_Float16)v;
    union { _Float16 h; unsigned short u; } cv; cv.h = h; return cv.u;
}
__device__ inline float h2f(unsigned short u){
    union { unsigned short u; _Float16 h; } cv; cv.u = u; return (float)cv.h;
}

// ================= fused prep (r16-proven, unchanged) =================
// A (blocks 0..391):   x -> xg[(b*2+g)][s][32ic fp16]
// B (blocks 392..663): x -> xpad[plane][68][72] fp16, zero halo
// C (blocks 664..859): w1 -> w1t[g][tap][oc][32ic] fp16  (parallel: thread per octet)
__global__ __launch_bounds__(256) void prep_all(
    const float* __restrict__ x, const float* __restrict__ w1,
    unsigned short* __restrict__ xg, unsigned short* __restrict__ w1t,
    unsigned short* __restrict__ xpad)
{
    int bb = blockIdx.x;
    if (bb < 392) {
        int t = bb * 256 + threadIdx.x;           // < 100352
        int g = t / NPIX;
        int pix = t - g * NPIX;
        int b = pix / HW; int s = pix - b * HW;
        const float* xp = x + (size_t)b * 64 * HW + (size_t)g * 32 * HW + s;
        unsigned short* dst = xg + ((size_t)(b * 2 + g) * HW + s) * 32;
#pragma unroll
        for (int p = 0; p < 4; ++p) {
            alignas(16) unsigned short tmp[8];
#pragma unroll
            for (int e = 0; e < 8; ++e)
                tmp[e] = f2h(xp[(size_t)(p * 8 + e) * HW]);
            *(u16x8*)(dst + p * 8) = *(const u16x8*)tmp;
        }
    } else if (bb < 664) {
        int t2 = (bb - 392) * 256 + threadIdx.x;  // < 69632
        int plane = t2 / 68; int r = t2 - plane * 68;
        unsigned short* dst = xpad + ((size_t)plane * 68 + r) * 72;
        int h = r - 6;
        alignas(16) unsigned short tmp[72];
#pragma unroll
        for (int i = 0; i < 72; ++i) tmp[i] = 0;
        if (h >= 0 && h < 56) {
            const float* src = x + (size_t)plane * HW + h * 56;
#pragma unroll
            for (int wq = 0; wq < 56; ++wq) tmp[6 + wq] = f2h(src[wq]);
        }
#pragma unroll
        for (int k = 0; k < 9; ++k)
            *(u16x8*)(dst + k * 8) = *(const u16x8*)(tmp + k * 8);
    } else {
        int t = (bb - 664) * 256 + threadIdx.x;   // < 50176 = 2*49*128*4
        int g = t / 25088;
        int r = t - g * 25088;                    // tap*512 + oc*4 + jo
        int tap = r / 512; int r2 = r - tap * 512;
        int oc = r2 >> 2; int jo = r2 & 3;
        unsigned short* dst = w1t + ((size_t)(g * 49 + tap) * 128 + oc) * 32 + jo * 8;
        alignas(16) unsigned short tmp[8];
#pragma unroll
        for (int e = 0; e < 8; ++e)
            tmp[e] = f2h(w1[((size_t)(oc * 64 + g * 32 + jo * 8 + e)) * 49 + tap]);
        *(u16x8*)dst = *(const u16x8*)tmp;
    }
}

// ================= conv1(full K, dual-resident halves) + conv2 + softmax =================
// grid 224 = (b16, rg14); block 512 = 8 waves; waves 0-3: g=0, waves 4-7: g=1
// r18 best-measured schedule: A/B 1-tap dbuf + sched_barrier(0) pins, no setprio
// attn output: [g][56-pad] fp16 where g = flat([B,49,HW])/49 (= out-flat/64 space)
// LDS: 2 planes x 16rows x 68sites x 72B = 156672 B (1 block/CU)
#define LOADA(Abuf, tap) do {                                                 \
    const int p_ = (tap) / 7, q_ = (tap) - 7 * ((tap) / 7);                   \
    const int off_ = p_ * 9792 + q_ * 144;                                    \
    _Pragma("unroll")                                                         \
    for (int mt = 0; mt < 7; ++mt)                                            \
        Abuf[mt] = *(const f16x8*)(smem + abase[mt] + off_);                  \
    } while (0)

#define LOADB(Bbuf, tap) do {                                                 \
    const unsigned short* p_ = wb + (size_t)(tap) * 4096;                     \
    Bbuf[0] = *(const f16x8*)(p_);                                            \
    Bbuf[1] = *(const f16x8*)(p_ + 512);                                      \
    Bbuf[2] = *(const f16x8*)(p_ + 1024);                                     \
    Bbuf[3] = *(const f16x8*)(p_ + 1536);                                     \
    } while (0)

#define DOMFMA(Abuf, Bbuf) do {                                               \
    _Pragma("unroll")                                                         \
    for (int mt = 0; mt < 7; ++mt) {                                          \
        acc[mt][0] = __builtin_amdgcn_mfma_f32_16x16x32_f16(Abuf[mt], Bbuf[0], acc[mt][0], 0, 0, 0); \
        acc[mt][1] = __builtin_amdgcn_mfma_f32_16x16x32_f16(Abuf[mt], Bbuf[1], acc[mt][1], 0, 0, 0); \
        acc[mt][2] = __builtin_amdgcn_mfma_f32_16x16x32_f16(Abuf[mt], Bbuf[2], acc[mt][2], 0, 0, 0); \
        acc[mt][3] = __builtin_amdgcn_mfma_f32_16x16x32_f16(Abuf[mt], Bbuf[3], acc[mt][3], 0, 0, 0); \
    }                                                                         \
    } while (0)

__global__ __launch_bounds__(512, 2) void conv_full(
    const unsigned short* __restrict__ xg, const unsigned short* __restrict__ w1t,
    const float* __restrict__ b1, const float* __restrict__ w2,
    const float* __restrict__ b2, unsigned short* __restrict__ attn2)
{
    __shared__ char smem[156672];                      // 2 x 78336
    unsigned short* k1sa = (unsigned short*)smem;            // [224][136] 60928 B (epilogue)
    unsigned short* w2s  = (unsigned short*)(smem + 60928);  // [64][136]  17408 B
    unsigned short* k1sb = (unsigned short*)(smem + 78336);  // [224][136] 60928 B

    const int blk = blockIdx.x;
    const int b   = blk / 14; const int rg = blk - b * 14;
    const int h0  = rg * 4;
    const int tid = threadIdx.x;
    const int lane = tid & 63, warp = tid >> 6;        // 8 waves
    const int g   = warp >> 2;                         // ic-half
    const int wm  = (warp >> 1) & 1, wn = warp & 1;
    const int oc0 = wn * 64;
    const int li  = lane & 15, j = lane >> 4;

    const unsigned short* xplane[2] = {
        xg + (size_t)(b * 2 + 0) * HW * 32,
        xg + (size_t)(b * 2 + 1) * HW * 32 };

    u16x8 zz; for (int e = 0; e < 8; ++e) zz[e] = 0;

    // ---- issue staged loads for BOTH planes (14 x 16B per thread) ----
    u16x8 sv[14];
#pragma unroll
    for (int u = 0; u < 14; ++u) {
        int i = u * 512 + tid;                         // < 7168 = 2*16*224
        int pl = i / 3584; int rem = i - pl * 3584;
        int row = rem / 224; int r2 = rem - row * 224;
        int site = r2 >> 2, chunk = r2 & 3;
        int hh = h0 - 6 + row;
        sv[u] = (hh >= 0 && hh < 56)
            ? *(const u16x8*)(xplane[pl] + ((size_t)hh * 56 + site) * 32 + chunk * 8)
            : zz;
    }

    // ---- zero all LDS (halos stay zero) ----
    {
        f32x4 zv = {0.f, 0.f, 0.f, 0.f};
#pragma unroll
        for (int u = 0; u < 20; ++u) {
            int i = u * 512 + tid;
            if (i < 9792) *(f32x4*)(smem + (size_t)i * 16) = zv;
        }
    }
    __syncthreads();

    // ---- write staged tiles (site stride 72B) ----
#pragma unroll
    for (int u = 0; u < 14; ++u) {
        int i = u * 512 + tid;
        int pl = i / 3584; int rem = i - pl * 3584;
        int row = rem / 224; int r2 = rem - row * 224;
        int site = r2 >> 2, chunk = r2 & 3;
        int hh = h0 - 6 + row;
        if (hh >= 0 && hh < 56)
            *(u16x8*)(smem + pl * 78336 + (row * 68 + 6 + site) * 72 + chunk * 16) = sv[u];
    }

    // ---- issue w2 loads (latency hidden under tap loop) ----
    f32x4 wv[4];
#pragma unroll
    for (int u = 0; u < 4; ++u) {
        int idx = u * 512 + tid;                       // f32x4 index, < 1568
        wv[u] = (idx < 1568) ? *(const f32x4*)(w2 + (size_t)idx * 4)
                             : (f32x4){0.f, 0.f, 0.f, 0.f};
    }
    __syncthreads();

    // ---- A base addresses (fixed across all taps; include plane offset) ----
    int abase[7];
#pragma unroll
    for (int mt = 0; mt < 7; ++mt) {
        int local = wm * 112 + mt * 16 + li;           // 0..223
        int rb = local / 56; int wp = local - rb * 56;
        abase[mt] = g * 78336 + (rb * 68 + wp) * 72 + j * 16;
    }

    f32x4 acc[7][4];
#pragma unroll
    for (int mt = 0; mt < 7; ++mt)
#pragma unroll
        for (int nt = 0; nt < 4; ++nt)
#pragma unroll
            for (int c = 0; c < 4; ++c) acc[mt][nt][c] = 0.f;

    // B base: w1t[g][tap][oc][32], oc = oc0 + li (+nt*16 via imm)
    const unsigned short* wb = w1t + ((size_t)g * 49 * 128 + oc0 + li) * 32 + j * 8;

    // ---- 49-tap fully-unrolled loop, 1-tap double buffer, pinned schedule ----
    {
        f16x8 A0[7], A1[7], B0[4], B1[4];
        LOADA(A0, 0); LOADB(B0, 0);
#pragma unroll
        for (int th = 0; th < 24; ++th) {
            LOADA(A1, 2 * th + 1); LOADB(B1, 2 * th + 1);
            __builtin_amdgcn_sched_barrier(0);
            DOMFMA(A0, B0);
            __builtin_amdgcn_sched_barrier(0);
            LOADA(A0, 2 * th + 2); LOADB(B0, 2 * th + 2);
            __builtin_amdgcn_sched_barrier(0);
            DOMFMA(A1, B1);
            __builtin_amdgcn_sched_barrier(0);
        }
        DOMFMA(A0, B0);                                // tap 48
    }

    __syncthreads();          // all staging readers done; LDS can be overlaid

    // ---- epilogue phase A: write k1 partials + w2s ----
    // g0 waves -> k1sa (+bias); g1 waves -> k1sb (no bias)
    {
        unsigned short* kb = g ? k1sb : k1sa;
        const int pixbase = wm * 112;
#pragma unroll
        for (int nt = 0; nt < 4; ++nt) {
            int oc = oc0 + nt * 16 + li;
            float bias = g ? 0.f : b1[oc];
#pragma unroll
            for (int mt = 0; mt < 7; ++mt) {
#pragma unroll
                for (int i = 0; i < 4; ++i) {
                    int px = pixbase + mt * 16 + j * 4 + i;
                    kb[px * 136 + oc] = f2h(acc[mt][nt][i] + bias);
                }
            }
        }
    }
    // w2s [64 taps][136] fp16 (rows >=49 garbage, masked later)
#pragma unroll
    for (int u = 0; u < 4; ++u) {
        int idx = u * 512 + tid;
        if (idx < 1568) {
            int a = idx / 32; int c0 = (idx - a * 32) * 4;
            alignas(8) unsigned short t4[4];
#pragma unroll
            for (int e = 0; e < 4; ++e) t4[e] = f2h(wv[u][e]);
            *(unsigned long long*)(w2s + a * 136 + c0) = *(const unsigned long long*)t4;
        }
    }
    __syncthreads();

    // ---- conv2: L[tap][px] = w2 @ (k1a + k1b), softmax over taps ----
    // output: attn2[g][56] fp16 with g = b*3136 + 64*r + s/49, col = s%49
    const int start = (warp < 6) ? warp * 2 : 12 + (warp - 6);
    const int cnt   = (warp < 6) ? 2 : 1;

#pragma unroll
    for (int u = 0; u < 2; ++u) {
        if (u < cnt) {
            int pxt = start + u;
            f32x4 a2[4];
#pragma unroll
            for (int tt = 0; tt < 4; ++tt)
#pragma unroll
                for (int c = 0; c < 4; ++c) a2[tt][c] = 0.f;
#pragma unroll
            for (int ks = 0; ks < 4; ++ks) {
                const f16x8 ba = *(const f16x8*)(k1sa + (pxt * 16 + li) * 136 + ks * 32 + j * 8);
                const f16x8 bbv = *(const f16x8*)(k1sb + (pxt * 16 + li) * 136 + ks * 32 + j * 8);
                const f16x8 bf = ba + bbv;             // packed fp16 add
#pragma unroll
                for (int tt = 0; tt < 4; ++tt) {
                    const f16x8 af = *(const f16x8*)(w2s + (tt * 16 + li) * 136 + ks * 32 + j * 8);
                    a2[tt] = __builtin_amdgcn_mfma_f32_16x16x32_f16(af, bf, a2[tt], 0, 0, 0);
                }
            }
            // softmax over taps (rows) for pixel col li
            float mx = -3e38f;
#pragma unroll
            for (int tt = 0; tt < 4; ++tt)
#pragma unroll
                for (int i = 0; i < 4; ++i) {
                    int r = tt * 16 + j * 4 + i;
                    float v = a2[tt][i] + ((r < 49) ? b2[r] : 0.f);
                    a2[tt][i] = v;
                    if (r < 49) mx = fmaxf(mx, v);
                }
            mx = fmaxf(mx, __shfl_xor(mx, 16));
            mx = fmaxf(mx, __shfl_xor(mx, 32));
            float sum = 0.f; float ex[16];
#pragma unroll
            for (int tt = 0; tt < 4; ++tt)
#pragma unroll
                for (int i = 0; i < 4; ++i) {
                    int r = tt * 16 + j * 4 + i;
                    float e = (r < 49) ? __expf(a2[tt][i] - mx) : 0.f;
                    ex[tt * 4 + i] = e; sum += e;
                }
            sum += __shfl_xor(sum, 16);
            sum += __shfl_xor(sum, 32);
            float inv = 1.f / sum;

            int s = rg * 224 + pxt * 16 + li;          // pixel within batch
            int s49 = s / 49; int sm = s - s49 * 49;
            unsigned short* ab2 = attn2 + ((size_t)b * 3136 + s49) * 56 + sm;
#pragma unroll
            for (int tt = 0; tt < 4; ++tt)
#pragma unroll
                for (int i = 0; i < 4; ++i) {
                    int r = tt * 16 + j * 4 + i;
                    if (r < 49) ab2[(size_t)r * 3584] = f2h(ex[tt * 4 + i] * inv);
                }
        }
    }
}

// ================= final grouped einsum, 8 outputs/thread; vectorized attn2 reads =================
__global__ __launch_bounds__(256) void gather_kernel(
    const unsigned short* __restrict__ xpad, const unsigned short* __restrict__ attn2,
    float* __restrict__ out)
{
    int tid = blockIdx.x * 256 + threadIdx.x;   // < 401408
    int plane = tid / 392;                      // b*64 + c
    int r1 = tid - plane * 392;
    int h = r1 / 7; int oct = r1 - h * 7; int w0 = oct * 8;
    int F0 = plane * HW + h * 56 + w0;

    // attn2[g][56], 16B-aligned rows (112B): 7 vector loads replace 49 scalars
    const unsigned short* ap = attn2 + (size_t)(F0 >> 6) * 56;
    u16x8 av[7];
#pragma unroll
    for (int u = 0; u < 7; ++u) av[u] = *(const u16x8*)(ap + u * 8);
    float a[49];
#pragma unroll
    for (int k = 0; k < 49; ++k) a[k] = h2f(av[k >> 3][k & 7]);

    const unsigned short* xp = xpad + (size_t)plane * (68 * 72) + w0;
    float o[8];
#pragma unroll
    for (int dw = 0; dw < 8; ++dw) o[dw] = 0.f;

#pragma unroll
    for (int p = 0; p < 7; ++p) {
        const unsigned short* rp = xp + (h + 2 * p) * 72;
        u16x8 v0 = *(const u16x8*)rp;
        u16x8 v1 = *(const u16x8*)(rp + 8);
        u16x8 v2 = *(const u16x8*)(rp + 16);
        float rr[20];
#pragma unroll
        for (int e = 0; e < 8; ++e) { rr[e] = h2f(v0[e]); rr[8 + e] = h2f(v1[e]); }
#pragma unroll
        for (int e = 0; e < 4; ++e) rr[16 + e] = h2f(v2[e]);
#pragma unroll
        for (int q = 0; q < 7; ++q) {
            float aq = a[p * 7 + q];
#pragma unroll
            for (int dw = 0; dw < 8; ++dw)
                o[dw] = fmaf(rr[dw + 2 * q], aq, o[dw]);
        }
    }

    f32x4 s0 = {o[0], o[1], o[2], o[3]};
    f32x4 s1 = {o[4], o[5], o[6], o[7]};
    *(f32x4*)(out + F0) = s0;
    *(f32x4*)(out + F0 + 4) = s1;
}

extern "C" void kernel_launch(void* const* d_in, const int* in_sizes, int n_in,
                              void* d_out, int out_size, void* d_ws, size_t ws_size,
                              hipStream_t stream)
{
    const float* x  = (const float*)d_in[0];
    const float* w1 = (const float*)d_in[1];
    const float* b1 = (const float*)d_in[2];
    const float* w2 = (const float*)d_in[3];
    const float* b2 = (const float*)d_in[4];
    float* out = (float*)d_out;

    unsigned short* attn2 = (unsigned short*)d_ws;             //  5.62 MB (50176 x 56 fp16)
    unsigned short* xg    = attn2 + (size_t)NPIX * 56;         //  6.42 MB
    unsigned short* w1t   = xg + (size_t)16 * 2 * HW * 32;     //  0.80 MB
    unsigned short* xpad  = w1t + (size_t)2 * 49 * 128 * 32;   // 10.03 MB (total ~22.9 MB)

    prep_all<<<860, 256, 0, stream>>>(x, w1, xg, w1t, xpad);
    conv_full<<<224, 512, 0, stream>>>(xg, w1t, b1, w2, b2, attn2);
    gather_kernel<<<1568, 256, 0, stream>>>(xpad, attn2, out);
}